// Round 2
// baseline (469.575 us; speedup 1.0000x reference)
//
#include <hip/hip_runtime.h>

#define TPB 640

typedef unsigned int u32;

namespace {
constexpr int WS_IMGS = 0;         // [12][36][768] f32
constexpr int WS_TXTS = 331776;    // [12][36][512] f32
constexpr int WS_CIMG = 552960;    // [36][768] f32
constexpr int WS_CTXT = 580608;    // [36][512] f32
}

__device__ __forceinline__ float gelu_f(float x) { return 0.5f * x * (1.0f + erff(x * 0.70710678118654752f)); }

struct P {
    const float *vpc, *vpm, *tpc, *tpm, *cpc, *cpi, *cpt;
    const float *lig, *lib, *ltg, *ltb;
    const float *iw1, *ib1, *iw2, *ib2;
    const float *tw1, *tb1, *tw2, *tb2;
    const float *ciw1, *cib1, *ciw2, *cib2;
    const float *ctw1, *ctb1, *ctw2, *ctb2;
    float* ws;
};

// Blocks 0..35: one (variant v, token t) row each; run all 12 depths internally.
// Blocks 36..71: common-prompt MLPs (cimg / ctxt) for one (v,t) row.
__global__ __launch_bounds__(TPB) void phase1_kernel(P p) {
    __shared__ float sx[1280];        // current x row (img[768] ++ txt[512])
    __shared__ float xln[2][1280];    // LN'd row for img-path / txt-path
    __shared__ float part[8][168];    // K-chunk partials (padded)
    __shared__ float hh[160];         // gelu'd hidden (80 img + 80 txt)
    __shared__ float redA[10], redB[10];
    __shared__ float s_stats[2];

    const int tid = threadIdx.x;
    const int blk = blockIdx.x;

    if (blk < 36) {
        const int v = blk / 12, t = blk % 12;
        const float* is = (v == 2) ? p.vpm : p.vpc;   // [12][768]
        const float* ts = (v == 1) ? p.tpm : p.tpc;   // [12][512]
        for (int k = tid; k < 768; k += TPB) sx[k] = is[t * 768 + k];
        for (int k = tid; k < 512; k += TPB) sx[768 + k] = ts[t * 512 + k];
        __syncthreads();

        for (int d = 0; d < 12; ++d) {
            // ---- LN stats over 1280 ----
            float s = 0.f, s2 = 0.f;
            for (int k = tid; k < 1280; k += TPB) { float x = sx[k]; s += x; s2 += x * x; }
            #pragma unroll
            for (int off = 32; off > 0; off >>= 1) { s += __shfl_down(s, off); s2 += __shfl_down(s2, off); }
            if ((tid & 63) == 0) { redA[tid >> 6] = s; redB[tid >> 6] = s2; }
            __syncthreads();
            if (tid == 0) {
                float S = 0.f, S2 = 0.f;
                #pragma unroll
                for (int w = 0; w < 10; ++w) { S += redA[w]; S2 += redB[w]; }
                float m = S * (1.0f / 1280.0f);
                float var = S2 * (1.0f / 1280.0f) - m * m;
                s_stats[0] = m; s_stats[1] = rsqrtf(var + 1e-5f);
            }
            __syncthreads();
            const float m = s_stats[0], rs = s_stats[1];
            // ---- two LayerNorm affines ----
            for (int k = tid; k < 1280; k += TPB) {
                float xc = (sx[k] - m) * rs;
                xln[0][k] = xc * p.lig[d * 1280 + k] + p.lib[d * 1280 + k];
                xln[1][k] = xc * p.ltg[d * 1280 + k] + p.ltb[d * 1280 + k];
            }
            __syncthreads();
            // ---- GEMV1: 1280 -> 80 (img) and 1280 -> 80 (txt), 2 outputs/thread ----
            {
                const int po = tid % 80, kc = tid / 80;   // kc in [0,8), Kc=160
                const int o0 = 2 * po;
                const int path = (o0 >= 80);
                const int j0 = path ? (o0 - 80) : o0;
                const float* xl = xln[path];
                const float* wp = (path ? p.tw1 : p.iw1) + (size_t)d * 1280 * 80 + (size_t)(kc * 160) * 80 + j0;
                const int k0 = kc * 160;
                float a0 = 0.f, a1 = 0.f;
                #pragma unroll 4
                for (int i = 0; i < 160; ++i) {
                    float2 wv = *reinterpret_cast<const float2*>(wp);
                    float xv = xl[k0 + i];
                    a0 += xv * wv.x;
                    a1 += xv * wv.y;
                    wp += 80;
                }
                part[kc][o0] = a0; part[kc][o0 + 1] = a1;
            }
            __syncthreads();
            if (tid < 160) {
                const int o = tid, path = (o >= 80), j = path ? o - 80 : o;
                float a = (path ? p.tb1 : p.ib1)[d * 80 + j];
                #pragma unroll
                for (int kc = 0; kc < 8; ++kc) a += part[kc][o];
                hh[o] = gelu_f(a);
            }
            __syncthreads();
            // ---- GEMV2: 80 -> 768 (img) / 80 -> 512 (txt), 2 outputs/thread ----
            if (tid < 384) {
                const int j0 = 2 * tid;
                const float* wp = p.iw2 + (size_t)d * 80 * 768 + j0;
                float a0 = p.ib2[d * 768 + j0], a1 = p.ib2[d * 768 + j0 + 1];
                #pragma unroll 4
                for (int kk = 0; kk < 80; ++kk) {
                    float2 wv = *reinterpret_cast<const float2*>(wp);
                    float hv = hh[kk];
                    a0 += hv * wv.x; a1 += hv * wv.y;
                    wp += 768;
                }
                sx[j0] = a0; sx[j0 + 1] = a1;
                *reinterpret_cast<float2*>(p.ws + WS_IMGS + ((size_t)d * 36 + blk) * 768 + j0) = make_float2(a0, a1);
            } else {
                const int j0 = 2 * tid - 768;
                const float* wp = p.tw2 + (size_t)d * 80 * 512 + j0;
                float a0 = p.tb2[d * 512 + j0], a1 = p.tb2[d * 512 + j0 + 1];
                #pragma unroll 4
                for (int kk = 0; kk < 80; ++kk) {
                    float2 wv = *reinterpret_cast<const float2*>(wp);
                    float hv = hh[80 + kk];
                    a0 += hv * wv.x; a1 += hv * wv.y;
                    wp += 512;
                }
                sx[768 + j0] = a0; sx[768 + j0 + 1] = a1;
                *reinterpret_cast<float2*>(p.ws + WS_TXTS + ((size_t)d * 36 + blk) * 512 + j0) = make_float2(a0, a1);
            }
            __syncthreads();
        }
    } else {
        // ---- common-prompt MLPs ----
        const int r = blk - 36;
        const int v = r / 12, t = r % 12;
        const float* cs = (v == 0) ? p.cpc : (v == 1) ? p.cpi : p.cpt;  // [12][512]
        for (int k = tid; k < 512; k += TPB) sx[k] = cs[t * 512 + k];
        __syncthreads();
        if (tid < 512) {
            const int o = tid % 64, kc = tid / 64;     // kc in [0,8), Kc=64
            const int path = (o >= 32), j = o & 31;
            const float* w = (path ? p.ctw1 : p.ciw1) + (size_t)(kc * 64) * 32 + j;
            float a = 0.f;
            #pragma unroll 4
            for (int i = 0; i < 64; ++i) { a += sx[kc * 64 + i] * w[0]; w += 32; }
            part[kc][o] = a;
        }
        __syncthreads();
        if (tid < 64) {
            const int o = tid, path = (o >= 32), j = o & 31;
            float a = (path ? p.ctb1 : p.cib1)[j];
            #pragma unroll
            for (int kc = 0; kc < 8; ++kc) a += part[kc][o];
            hh[o] = gelu_f(a);
        }
        __syncthreads();
        if (tid < 384) {
            const int j0 = 2 * tid;
            const float* wp = p.ciw2 + j0;     // [32][768]
            float a0 = p.cib2[j0], a1 = p.cib2[j0 + 1];
            #pragma unroll
            for (int kk = 0; kk < 32; ++kk) {
                float2 wv = *reinterpret_cast<const float2*>(wp);
                float hv = hh[kk];
                a0 += hv * wv.x; a1 += hv * wv.y;
                wp += 768;
            }
            *reinterpret_cast<float2*>(p.ws + WS_CIMG + (size_t)r * 768 + j0) = make_float2(a0, a1);
        } else {
            const int j0 = 2 * tid - 768;
            const float* wp = p.ctw2 + j0;     // [32][512]
            float a0 = p.ctb2[j0], a1 = p.ctb2[j0 + 1];
            #pragma unroll
            for (int kk = 0; kk < 32; ++kk) {
                float2 wv = *reinterpret_cast<const float2*>(wp);
                float hv = hh[32 + kk];
                a0 += hv * wv.x; a1 += hv * wv.y;
                wp += 512;
            }
            *reinterpret_cast<float2*>(p.ws + WS_CTXT + (size_t)r * 512 + j0) = make_float2(a0, a1);
        }
    }
}

// Broadcast/gather to the big f32 outputs, 4 elems (16 B) per thread-iteration.
__global__ __launch_bounds__(256) void emit_kernel(const int* __restrict__ mt,
                                                   const float* __restrict__ ws,
                                                   float* __restrict__ out) {
    constexpr unsigned int C0 = 512u * 24 * 192;       // img0  [512][24][768] /4
    constexpr unsigned int C1 = 512u * 24 * 128;       // txt0  [512][24][512] /4
    constexpr unsigned int C2 = 11u * 512 * 12 * 192;  // imgs  [11][512][12][768] /4
    constexpr unsigned int C3 = 11u * 512 * 12 * 128;  // txts  [11][512][12][512] /4
    constexpr unsigned int TOT = C0 + C1 + C2 + C3;    // 25,559,040 chunks
    const unsigned int stride = gridDim.x * blockDim.x;
    for (unsigned int c = blockIdx.x * blockDim.x + threadIdx.x; c < TOT; c += stride) {
        const float* src;
        if (c < C0) {
            unsigned int b = c / 4608u, r = c % 4608u;        // 24*192
            unsigned int tok = r / 192u, col = (r % 192u) * 4u;
            int v = mt[b];
            src = (tok < 12u) ? ws + WS_IMGS + ((size_t)v * 12 + tok) * 768 + col
                              : ws + WS_CIMG + ((size_t)v * 12 + (tok - 12u)) * 768 + col;
        } else if (c < C0 + C1) {
            unsigned int cc = c - C0;
            unsigned int b = cc / 3072u, r = cc % 3072u;      // 24*128
            unsigned int tok = r / 128u, col = (r % 128u) * 4u;
            int v = mt[b];
            src = (tok < 12u) ? ws + WS_TXTS + ((size_t)v * 12 + tok) * 512 + col
                              : ws + WS_CTXT + ((size_t)v * 12 + (tok - 12u)) * 512 + col;
        } else if (c < C0 + C1 + C2) {
            unsigned int cc = c - C0 - C1;
            unsigned int d = cc / 1179648u, r = cc % 1179648u;  // 512*12*192
            unsigned int b = r / 2304u, rr = r % 2304u;         // 12*192
            unsigned int tok = rr / 192u, col = (rr % 192u) * 4u;
            int v = mt[b];
            src = ws + WS_IMGS + ((size_t)(d + 1) * 36 + v * 12 + tok) * 768 + col;
        } else {
            unsigned int cc = c - C0 - C1 - C2;
            unsigned int d = cc / 786432u, r = cc % 786432u;    // 512*12*128
            unsigned int b = r / 1536u, rr = r % 1536u;         // 12*128
            unsigned int tok = rr / 128u, col = (rr % 128u) * 4u;
            int v = mt[b];
            src = ws + WS_TXTS + ((size_t)(d + 1) * 36 + v * 12 + tok) * 512 + col;
        }
        float4 f = *reinterpret_cast<const float4*>(src);
        *reinterpret_cast<float4*>(out + (size_t)c * 4) = f;
    }
}

extern "C" void kernel_launch(void* const* d_in, const int* in_sizes, int n_in,
                              void* d_out, int out_size, void* d_ws, size_t ws_size,
                              hipStream_t stream) {
    const int* mt = (const int*)d_in[0];
    P p;
    p.vpc  = (const float*)d_in[1];
    p.vpm  = (const float*)d_in[2];
    p.tpc  = (const float*)d_in[3];
    p.tpm  = (const float*)d_in[4];
    p.cpc  = (const float*)d_in[5];
    p.cpi  = (const float*)d_in[6];
    p.cpt  = (const float*)d_in[7];
    p.lig  = (const float*)d_in[8];
    p.lib  = (const float*)d_in[9];
    p.ltg  = (const float*)d_in[10];
    p.ltb  = (const float*)d_in[11];
    p.iw1  = (const float*)d_in[12];
    p.ib1  = (const float*)d_in[13];
    p.iw2  = (const float*)d_in[14];
    p.ib2  = (const float*)d_in[15];
    p.tw1  = (const float*)d_in[16];
    p.tb1  = (const float*)d_in[17];
    p.tw2  = (const float*)d_in[18];
    p.tb2  = (const float*)d_in[19];
    p.ciw1 = (const float*)d_in[20];
    p.cib1 = (const float*)d_in[21];
    p.ciw2 = (const float*)d_in[22];
    p.cib2 = (const float*)d_in[23];
    p.ctw1 = (const float*)d_in[24];
    p.ctb1 = (const float*)d_in[25];
    p.ctw2 = (const float*)d_in[26];
    p.ctb2 = (const float*)d_in[27];
    p.ws   = (float*)d_ws;

    phase1_kernel<<<dim3(72), dim3(TPB), 0, stream>>>(p);
    emit_kernel<<<dim3(4096), dim3(256), 0, stream>>>(mt, (const float*)d_ws, (float*)d_out);
}